// Round 11
// baseline (325.059 us; speedup 1.0000x reference)
//
#include <hip/hip_runtime.h>
#include <stdint.h>

typedef __attribute__((ext_vector_type(8))) short short8;
typedef __attribute__((ext_vector_type(4))) short short4v;
typedef __attribute__((ext_vector_type(4))) float floatx4;
typedef __attribute__((ext_vector_type(8))) _Float16 half8;
typedef __attribute__((ext_vector_type(2))) __fp16 pk2;

#define SEQ 2048
#define NTOK 8192
// 0.25 * log2(e): folds the 1/sqrt(H) quirk-scale and exp->exp2 into Q proj.
#define QSCALE 0.360673760222241f

__device__ __forceinline__ float b2f(unsigned short u){
  union { unsigned int i; float f; } v; v.i = ((unsigned int)u) << 16; return v.f;
}
__device__ __forceinline__ unsigned short f2b(float f){
  union { float f; unsigned int i; } v; v.f = f;
  unsigned int r = v.i + 0x7fffu + ((v.i >> 16) & 1u);
  return (unsigned short)(r >> 16);
}
// async global->LDS, 16B per lane. Dest = wave-uniform base + lane*16.
__device__ __forceinline__ void async16(const unsigned short* g, unsigned short* l){
  __builtin_amdgcn_global_load_lds(
      (const __attribute__((address_space(1))) unsigned int*)g,
      (__attribute__((address_space(3))) unsigned int*)l, 16, 0, 0);
}

// ---------- fused prep: convert_x | transpose_w | bias_concat --------------
__global__ __launch_bounds__(256) void prep_kernel(
    const float* __restrict__ x,
    const float* __restrict__ wq, const float* __restrict__ wk,
    const float* __restrict__ wv, const float* __restrict__ wo,
    const float* __restrict__ bq, const float* __restrict__ bk,
    const float* __restrict__ bv,
    unsigned short* __restrict__ xb,
    unsigned short* __restrict__ wqkvT, unsigned short* __restrict__ woT,
    float* __restrict__ bqkv)
{
  __shared__ unsigned short lT[64][72];
  const int bid = blockIdx.x;
  const int tid = threadIdx.x;
  if (bid < 8192){
    int i = (bid*256 + tid)*4;
    float4 v = *(const float4*)(x + i);
    short4v o;
    o[0] = (short)f2b(v.x); o[1] = (short)f2b(v.y);
    o[2] = (short)f2b(v.z); o[3] = (short)f2b(v.w);
    *(short4v*)(xb + i) = o;
  } else if (bid < 9216){
    int idx = bid - 8192;
    int sel = idx >> 8, rest = idx & 255;
    const float* src = (sel==0)?wq:(sel==1)?wk:(sel==2)?wv:wo;
    unsigned short* dst = (sel<3) ? (wqkvT + (size_t)sel*1024*1024) : woT;
    int n0 = (rest & 15) * 64, k0 = (rest >> 4) * 64;
#pragma unroll
    for (int i=0;i<4;i++){
      int ch = tid + i*256;
      int r = ch>>4, c = (ch&15)*4;
      float4 v = *(const float4*)(src + (size_t)(k0+r)*1024 + n0 + c);
      lT[r][c+0] = f2b(v.x); lT[r][c+1] = f2b(v.y);
      lT[r][c+2] = f2b(v.z); lT[r][c+3] = f2b(v.w);
    }
    __syncthreads();
#pragma unroll
    for (int i=0;i<2;i++){
      int ch = tid + i*256;
      int rn = ch>>3, c = (ch&7)*8;
      short8 v;
#pragma unroll
      for (int j=0;j<8;j++) v[j] = (short)lT[c+j][rn];
      *(short8*)(dst + (size_t)(n0+rn)*1024 + k0 + c) = v;
    }
  } else {
    int i = (bid - 9216)*256 + tid;
    if (i < 3072){
      int sel = i >> 10, j = i & 1023;
      bqkv[i] = (sel==0)?bq[j]:(sel==1)?bk[j]:bv[j];
    }
  }
}

// ---------------- GEMM: C(MxN) = A(MxK) @ Bt(NxK)^T + bias ----------------
// MODE 1: f32 store. MODE 3: QKV fused — cols<1024 bf16*QSCALE, 1024..2047
// bf16, >=2048 (V) written f16 TRANSPOSED into Vt[(b*16+h)*64+dv][s].
// R11: depth-2 prefetch, counted vmcnt (T4). 3 LDS buffers; iter t issues
// batch t+2, computes t, then ONE fused "s_waitcnt vmcnt(8); s_barrier"
// (8 = the just-issued batch's loads/thread) — batch t+1 thus had a full
// iteration + barrier (~2000+ cyc) to land vs the 2-phase scheme's single
// ~600-cyc compute span (measured 3300 cyc/step vs ~900 busy = ~70% stall).
// Race audit: writes->buf[(t+2)%3] follow barrier(t) whose readers (t-1)
// are done; reads of buf[t%3] are covered because every wave executed
// vmcnt(8)+barrier at end of t-1 (barrier publishes per-wave vmcnt).
// Tail: second-to-last iter waits vmcnt(0); last iter needs no sync.
// Staging geometry / fragments / epilogue byte-identical to the verified
// R10 kernel. LDS 96KB -> 1 block/CU (4 waves): accepted, depth-2 removes
// the stall the extra occupancy was hiding.
template<int MODE>
__global__ __launch_bounds__(256) void gemm_bt_kernel(
    const unsigned short* __restrict__ A,
    const unsigned short* __restrict__ Bt,
    const float* __restrict__ bias,
    void* __restrict__ Cv,
    unsigned short* __restrict__ Vt,
    int M, int N, int K)
{
  __shared__ unsigned short lA[3][128*64];
  __shared__ unsigned short lB[3][128*64];
  const int tid  = threadIdx.x;
  const int lane = tid & 63;
  const int wave = tid >> 6;
  const int quad = lane >> 4;
  const int l15  = lane & 15;
  const int wR = (wave >> 1) * 64;
  const int wC = (wave & 1) * 64;
  const int rowB = blockIdx.y * 128;
  const int colB = blockIdx.x * 128;

  const int srow = wave*32 + (lane>>3);
  const int sc8  = (lane&7) ^ (lane>>3);
  const unsigned short* gA = A  + (size_t)(rowB + srow)*K + sc8*8;
  const unsigned short* gB = Bt + (size_t)(colB + srow)*K + sc8*8;
  const int woff = wave*2048 + lane*8;

  floatx4 acc[4][4];
#pragma unroll
  for (int t=0;t<4;t++)
#pragma unroll
    for (int u=0;u<4;u++) acc[t][u] = (floatx4){0.f,0.f,0.f,0.f};

  // prologue: stage tiles 0 and 1 into buffers 0 and 1, then ensure tile 0
  // landed (vmcnt(8) leaves tile 1's 8 loads in flight).
#pragma unroll
  for (int i=0;i<4;i++){
    async16(gA + (size_t)i*8*K, &lA[0][0] + woff + i*512);
    async16(gB + (size_t)i*8*K, &lB[0][0] + woff + i*512);
  }
#pragma unroll
  for (int i=0;i<4;i++){
    async16(gA + (size_t)i*8*K + 64, &lA[1][0] + woff + i*512);
    async16(gB + (size_t)i*8*K + 64, &lB[1][0] + woff + i*512);
  }
  asm volatile("s_waitcnt vmcnt(8)\n\ts_barrier" ::: "memory");

  int cur = 0, nxt2 = 2;
  for (int kt = 0; kt < K; kt += 64){
    if (kt + 128 < K){                  // issue batch t+2 -> buf[(t+2)%3]
      unsigned short* an = &lA[nxt2][0] + woff;
      unsigned short* bn = &lB[nxt2][0] + woff;
#pragma unroll
      for (int i=0;i<4;i++){
        async16(gA + (size_t)i*8*K + kt + 128, an + i*512);
        async16(gB + (size_t)i*8*K + kt + 128, bn + i*512);
      }
    }
    const unsigned short* sA = &lA[cur][0];
    const unsigned short* sB = &lB[cur][0];
#pragma unroll
    for (int ks=0; ks<2; ks++){
      const int cph = ((ks*4 + quad) ^ (l15 & 7)) * 8;
      short8 af[4], bf[4];
#pragma unroll
      for (int t=0;t<4;t++) af[t] = *(const short8*)(sA + (wR + t*16 + l15)*64 + cph);
#pragma unroll
      for (int u=0;u<4;u++) bf[u] = *(const short8*)(sB + (wC + u*16 + l15)*64 + cph);
#pragma unroll
      for (int t=0;t<4;t++)
#pragma unroll
        for (int u=0;u<4;u++)
          acc[t][u] = __builtin_amdgcn_mfma_f32_16x16x32_bf16(af[t], bf[u], acc[t][u], 0, 0, 0);
    }
    if (kt + 128 < K){
      asm volatile("s_waitcnt vmcnt(8)\n\ts_barrier" ::: "memory");
    } else if (kt + 64 < K){
      asm volatile("s_waitcnt vmcnt(0)\n\ts_barrier" ::: "memory");
    } // last iter: acc-only epilogue follows, no LDS hazard -> no sync
    cur  = (cur  == 2) ? 0 : cur  + 1;
    nxt2 = (nxt2 == 2) ? 0 : nxt2 + 1;
  }
  // epilogue: C/D layout col = lane&15, row = quad*4 + r  [m89/m91 verified]
  if (MODE == 3 && colB >= 2048){
    // V block: transposed f16 store, 4 consecutive tokens per 8B chunk
#pragma unroll
    for (int u=0;u<4;u++){
      int col = colB + wC + u*16 + l15;
      float bval = bias[col];
      int vcol = col - 2048;
      int hh = vcol >> 6, dv = vcol & 63;
#pragma unroll
      for (int t=0;t<4;t++){
        int row0 = rowB + wR + t*16 + quad*4;       // token of acc[t][u][0]
        int bb = row0 >> 11, s = row0 & 2047;
        union { pk2 p[2]; short4v s4; } cv;
        cv.p[0] = __builtin_amdgcn_cvt_pkrtz(acc[t][u][0]+bval, acc[t][u][1]+bval);
        cv.p[1] = __builtin_amdgcn_cvt_pkrtz(acc[t][u][2]+bval, acc[t][u][3]+bval);
        *(short4v*)(Vt + ((size_t)(bb*16+hh)*64 + dv)*2048 + s) = cv.s4;
      }
    }
  } else {
#pragma unroll
    for (int u=0;u<4;u++){
      int col = colB + wC + u*16 + l15;
      float bval = bias[col];
      float scale = (MODE == 3 && col < 1024) ? QSCALE : 1.0f;
#pragma unroll
      for (int t=0;t<4;t++){
        int row0 = rowB + wR + t*16 + quad*4;
#pragma unroll
        for (int r=0;r<4;r++){
          float val = (acc[t][u][r] + bval) * scale;
          if (MODE == 1) ((float*)Cv)[(size_t)(row0 + r)*N + col] = val;
          else ((unsigned short*)Cv)[(size_t)(row0 + r)*N + col] = f2b(val);
        }
      }
    }
  }
}

// ---------------- flash attention forward, S^T formulation -----------------
// R9/R10 (verified): QBLK=256, 8 waves, true double-buffer, 1 barrier/tile,
// sigma-staged K -> in-lane full-rate x32 f16 PV, ones-column MFMA softmax
// denominator, V in per-half [64][64] sub-arrays (zero bank conflicts).
__global__ __launch_bounds__(512) void flash_attn_kernel(
    const unsigned short* __restrict__ qkv,
    const unsigned short* __restrict__ vt,      // f16 bits, [bh*64+dv][token]
    unsigned short* __restrict__ attn_out)      // bf16
{
  __shared__ __align__(16) unsigned short sK [2][128][64];    // bf16 [buf][sigma(kv)][dk]
  __shared__ __align__(16) unsigned short sVt[2][2][64][64];  // f16  [buf][hf][dv][kv64]
  const int bh = blockIdx.x;
  const int b = bh >> 4, h = bh & 15;
  const int qt = blockIdx.y;
  const int tid = threadIdx.x;
  const int wave = tid >> 6;
  const int lane = tid & 63;
  const int quad = lane >> 4, l15 = lane & 15;
  const int tok0 = b*SEQ + qt*256;

  // Q B-fragments straight from global (n = q = l15, k contiguous)
  short8 qf[2][2];
#pragma unroll
  for (int t=0;t<2;t++)
#pragma unroll
    for (int ks=0;ks<2;ks++)
      qf[t][ks] = *(const short8*)(qkv + (size_t)(tok0 + wave*32 + t*16 + l15)*3072
                                   + h*64 + ks*32 + quad*8);

  floatx4 oacc[2][4];
  floatx4 dacc[2];
#pragma unroll
  for (int t=0;t<2;t++){
    dacc[t] = (floatx4){0.f,0.f,0.f,0.f};
#pragma unroll
    for (int v=0;v<4;v++) oacc[t][v] = (floatx4){0.f,0.f,0.f,0.f};
  }
  const _Float16 one_h = (_Float16)1.0f;
  const half8 ones = {one_h,one_h,one_h,one_h,one_h,one_h,one_h,one_h};

  // staging descriptors: 2 K-chunks + 2 V-chunks per thread (512 threads).
  // K: [128 kv][64 dk]; row sigma-permuted (bits 5,6 pass through), chunk
  // XOR-swizzled by physical row &7.
  // V: [hf][64 dv][64 kv]; chunk c3 XOR dv&7 within the hf sub-array.
  const unsigned short* kbase[2]; const unsigned short* vbase[2];
  int KD[2], VD[2];
#pragma unroll
  for (int i=0;i<2;i++){
    int c = tid + i*512;
    int kr = c >> 3, kc = c & 7;
    int sr = (kr & 96) | ((kr & 4) << 2) | ((kr >> 1) & 12) | (kr & 3);
    kbase[i] = qkv + (size_t)(b*SEQ + kr)*3072 + 1024 + h*64 + kc*8;
    KD[i] = sr*64 + ((kc ^ (sr & 7)) * 8);
    int dv = c >> 4, vc = c & 15;
    int hfb = vc >> 3, c3 = vc & 7;
    vbase[i] = vt + (size_t)(bh*64 + dv)*2048 + vc*8;
    VD[i] = hfb*4096 + dv*64 + ((c3 ^ (dv & 7)) * 8);
  }
  short8 rk[2], rv[2];
  // prefetch tile 0
#pragma unroll
  for (int i=0;i<2;i++){
    rk[i] = *(const short8*)(kbase[i]);
    rv[i] = *(const short8*)(vbase[i]);
  }

  for (int it = 0; it < SEQ/128; it++){
    unsigned short* sKb = &sK [it & 1][0][0];
    unsigned short* sVb = &sVt[it & 1][0][0][0];
#pragma unroll
    for (int i=0;i<2;i++){
      *(short8*)(sKb + KD[i]) = rk[i];
      *(short8*)(sVb + VD[i]) = rv[i];
    }
    __syncthreads();
    if (it + 1 < SEQ/128){             // issue next-tile loads (in flight
      int nx = (it + 1) * 128;         //  across the whole compute phase)
#pragma unroll
      for (int i=0;i<2;i++){
        rk[i] = *(const short8*)(kbase[i] + (size_t)nx*3072);
        rv[i] = *(const short8*)(vbase[i] + nx);
      }
    }

#pragma unroll
    for (int hf=0; hf<2; hf++){
      // S^T[srow][q]: A = K (m = sigma(kv)), B = Q (n = q = l15).
      floatx4 sacc[4][2];
#pragma unroll
      for (int u=0;u<4;u++)
#pragma unroll
        for (int t=0;t<2;t++) sacc[u][t] = (floatx4){0.f,0.f,0.f,0.f};
#pragma unroll
      for (int ks=0;ks<2;ks++){
        short8 kf[4];
#pragma unroll
        for (int u=0;u<4;u++)
          kf[u] = *(const short8*)(sKb + (hf*64 + u*16 + l15)*64
                                   + ((ks*4 + quad) ^ (l15 & 7)) * 8);
#pragma unroll
        for (int u=0;u<4;u++)
#pragma unroll
          for (int t=0;t<2;t++)
            sacc[u][t] = __builtin_amdgcn_mfma_f32_16x16x32_bf16(kf[u], qf[t][ks], sacc[u][t], 0,0,0);
      }

      // p = 2^s; sacc[u][t] reg r holds kv = 32*(u>>1) + 8*quad + 4*(u&1) + r
      unsigned pw[4][2][2];
#pragma unroll
      for (int t=0;t<2;t++){
#pragma unroll
        for (int u=0;u<4;u++){
          float p0 = __builtin_amdgcn_exp2f(sacc[u][t][0]);
          float p1 = __builtin_amdgcn_exp2f(sacc[u][t][1]);
          float p2 = __builtin_amdgcn_exp2f(sacc[u][t][2]);
          float p3 = __builtin_amdgcn_exp2f(sacc[u][t][3]);
          union { pk2 p; unsigned u32; } c0, c1;
          c0.p = __builtin_amdgcn_cvt_pkrtz(p0,p1);
          c1.p = __builtin_amdgcn_cvt_pkrtz(p2,p3);
          pw[u][t][0] = c0.u32; pw[u][t][1] = c1.u32;
        }
      }
      // x32 f16 A-frags: pf[t][B] elem j = P[q][kv=32B+8quad+j], in-lane
      half8 pf[2][2];
#pragma unroll
      for (int t=0;t<2;t++)
#pragma unroll
        for (int B=0;B<2;B++){
          union { unsigned u32[4]; half8 h; } a;
          a.u32[0] = pw[2*B  ][t][0]; a.u32[1] = pw[2*B  ][t][1];
          a.u32[2] = pw[2*B+1][t][0]; a.u32[3] = pw[2*B+1][t][1];
          pf[t][B] = a.h;
        }

      // softmax denominator via ones-column MFMA: dacc rows q-aligned w/ oacc
#pragma unroll
      for (int t=0;t<2;t++)
#pragma unroll
        for (int B=0;B<2;B++)
          dacc[t] = __builtin_amdgcn_mfma_f32_16x16x32_f16(pf[t][B], ones, dacc[t], 0,0,0);

      // O[q][dv] += P V : B-frag = V[kv=32B+8quad+j][dv=v*16+l15], one b128
      // from the hf sub-array (128B rows — zero-conflict verified geometry)
#pragma unroll
      for (int v=0;v<4;v++){
#pragma unroll
        for (int B=0;B<2;B++){
          union { short8 s; half8 h; } vb;
          vb.s = *(const short8*)(sVb + hf*4096 + (v*16 + l15)*64
                                  + ((B*4 + quad) ^ (l15 & 7)) * 8);
#pragma unroll
          for (int t=0;t<2;t++)
            oacc[t][v] = __builtin_amdgcn_mfma_f32_16x16x32_f16(pf[t][B], vb.h, oacc[t][v], 0,0,0);
        }
      }
    }
  }

  // epilogue: O rows are q local = quad*4+r; dacc[t][r] holds that row's sum
#pragma unroll
  for (int t=0;t<2;t++){
#pragma unroll
    for (int r=0;r<4;r++){
      float inv = 1.0f / dacc[t][r];
      int tok = tok0 + wave*32 + t*16 + quad*4 + r;
#pragma unroll
      for (int v=0;v<4;v++)
        attn_out[(size_t)tok*1024 + h*64 + v*16 + l15] = f2b(oacc[t][v][r] * inv);
    }
  }
}

extern "C" void kernel_launch(void* const* d_in, const int* in_sizes, int n_in,
                              void* d_out, int out_size, void* d_ws, size_t ws_size,
                              hipStream_t stream)
{
  const float* x  = (const float*)d_in[0];
  const float* wq = (const float*)d_in[1];
  const float* bq = (const float*)d_in[2];
  const float* wk = (const float*)d_in[3];
  const float* bk = (const float*)d_in[4];
  const float* wv = (const float*)d_in[5];
  const float* bv = (const float*)d_in[6];
  const float* wo = (const float*)d_in[7];
  const float* bo = (const float*)d_in[8];
  float* out = (float*)d_out;

  char* ws = (char*)d_ws;
  unsigned short* wqkvT  = (unsigned short*)(ws);               // 3072x1024 bf16
  unsigned short* woT    = (unsigned short*)(ws + 6291456);     // 1024x1024 bf16
  float*          bqkv   = (float*)(ws + 8388608);              // 3072 f32
  unsigned short* xb     = (unsigned short*)(ws + 8400896);     // 8192x1024 bf16
  unsigned short* qkvbuf = (unsigned short*)(ws + 25178112);    // 8192x3072 bf16 (V region unused)
  unsigned short* vtbuf  = (unsigned short*)(ws + 75509760);    // 4096x2048 f16
  unsigned short* aobuf  = (unsigned short*)(ws + 92286976);    // 8192x1024 bf16

  prep_kernel<<<dim3(9228), 256, 0, stream>>>(x, wq, wk, wv, wo, bq, bk, bv,
                                              xb, wqkvT, woT, bqkv);
  gemm_bt_kernel<3><<<dim3(24, 64), 256, 0, stream>>>(xb, wqkvT, bqkv, qkvbuf, vtbuf,
                                                      8192, 3072, 1024);
  flash_attn_kernel<<<dim3(64, 8), 512, 0, stream>>>(qkvbuf, vtbuf, aobuf);
  gemm_bt_kernel<1><<<dim3(8, 64), 256, 0, stream>>>(aobuf, woT, bo, out, nullptr,
                                                     8192, 1024, 1024);
}

// Round 12
// 276.704 us; speedup vs baseline: 1.1748x; 1.1748x over previous
//
#include <hip/hip_runtime.h>
#include <stdint.h>

typedef __attribute__((ext_vector_type(8))) short short8;
typedef __attribute__((ext_vector_type(4))) short short4v;
typedef __attribute__((ext_vector_type(4))) float floatx4;
typedef __attribute__((ext_vector_type(8))) _Float16 half8;
typedef __attribute__((ext_vector_type(2))) __fp16 pk2;

#define SEQ 2048
#define NTOK 8192
// 0.25 * log2(e): folds the 1/sqrt(H) quirk-scale and exp->exp2 into Q proj.
#define QSCALE 0.360673760222241f

__device__ __forceinline__ float b2f(unsigned short u){
  union { unsigned int i; float f; } v; v.i = ((unsigned int)u) << 16; return v.f;
}
__device__ __forceinline__ unsigned short f2b(float f){
  union { float f; unsigned int i; } v; v.f = f;
  unsigned int r = v.i + 0x7fffu + ((v.i >> 16) & 1u);
  return (unsigned short)(r >> 16);
}
// async global->LDS, 16B per lane. Dest = wave-uniform base + lane*16.
__device__ __forceinline__ void async16(const unsigned short* g, unsigned short* l){
  __builtin_amdgcn_global_load_lds(
      (const __attribute__((address_space(1))) unsigned int*)g,
      (__attribute__((address_space(3))) unsigned int*)l, 16, 0, 0);
}

// ---------- fused prep: convert_x | transpose_w | bias_concat --------------
__global__ __launch_bounds__(256) void prep_kernel(
    const float* __restrict__ x,
    const float* __restrict__ wq, const float* __restrict__ wk,
    const float* __restrict__ wv, const float* __restrict__ wo,
    const float* __restrict__ bq, const float* __restrict__ bk,
    const float* __restrict__ bv,
    unsigned short* __restrict__ xb,
    unsigned short* __restrict__ wqkvT, unsigned short* __restrict__ woT,
    float* __restrict__ bqkv)
{
  __shared__ unsigned short lT[64][72];
  const int bid = blockIdx.x;
  const int tid = threadIdx.x;
  if (bid < 8192){
    int i = (bid*256 + tid)*4;
    float4 v = *(const float4*)(x + i);
    short4v o;
    o[0] = (short)f2b(v.x); o[1] = (short)f2b(v.y);
    o[2] = (short)f2b(v.z); o[3] = (short)f2b(v.w);
    *(short4v*)(xb + i) = o;
  } else if (bid < 9216){
    int idx = bid - 8192;
    int sel = idx >> 8, rest = idx & 255;
    const float* src = (sel==0)?wq:(sel==1)?wk:(sel==2)?wv:wo;
    unsigned short* dst = (sel<3) ? (wqkvT + (size_t)sel*1024*1024) : woT;
    int n0 = (rest & 15) * 64, k0 = (rest >> 4) * 64;
#pragma unroll
    for (int i=0;i<4;i++){
      int ch = tid + i*256;
      int r = ch>>4, c = (ch&15)*4;
      float4 v = *(const float4*)(src + (size_t)(k0+r)*1024 + n0 + c);
      lT[r][c+0] = f2b(v.x); lT[r][c+1] = f2b(v.y);
      lT[r][c+2] = f2b(v.z); lT[r][c+3] = f2b(v.w);
    }
    __syncthreads();
#pragma unroll
    for (int i=0;i<2;i++){
      int ch = tid + i*256;
      int rn = ch>>3, c = (ch&7)*8;
      short8 v;
#pragma unroll
      for (int j=0;j<8;j++) v[j] = (short)lT[c+j][rn];
      *(short8*)(dst + (size_t)(n0+rn)*1024 + k0 + c) = v;
    }
  } else {
    int i = (bid - 9216)*256 + tid;
    if (i < 3072){
      int sel = i >> 10, j = i & 1023;
      bqkv[i] = (sel==0)?bq[j]:(sel==1)?bk[j]:bv[j];
    }
  }
}

// ---------------- GEMM: C(MxN) = A(MxK) @ Bt(NxK)^T + bias ----------------
// MODE 1: f32 store. MODE 3: QKV fused — cols<1024 bf16*QSCALE, 1024..2047
// bf16, >=2048 (V) written f16 TRANSPOSED into Vt[(b*16+h)*64+dv][s].
// R12: REVERT to the R10 2-buffer/one-barrier schedule (best measured:
// gemm<3> ~66us, 2 blocks/CU). R11's 3-buffer depth-2 (96KB LDS) dropped
// occupancy to 1 wave/SIMD and regressed 66->119us — on this structure,
// LDS-funded pipeline depth loses to cross-wave overlap (m132-class lesson).
// Micro-opt kept: the FINAL iteration skips __syncthreads (uniform cond;
// epilogue touches only acc/global — no LDS hazard).
template<int MODE>
__global__ __launch_bounds__(256) void gemm_bt_kernel(
    const unsigned short* __restrict__ A,
    const unsigned short* __restrict__ Bt,
    const float* __restrict__ bias,
    void* __restrict__ Cv,
    unsigned short* __restrict__ Vt,
    int M, int N, int K)
{
  __shared__ unsigned short lA[2][128*64];
  __shared__ unsigned short lB[2][128*64];
  const int tid  = threadIdx.x;
  const int lane = tid & 63;
  const int wave = tid >> 6;
  const int quad = lane >> 4;
  const int l15  = lane & 15;
  const int wR = (wave >> 1) * 64;
  const int wC = (wave & 1) * 64;
  const int rowB = blockIdx.y * 128;
  const int colB = blockIdx.x * 128;

  const int srow = wave*32 + (lane>>3);
  const int sc8  = (lane&7) ^ (lane>>3);
  const unsigned short* gA = A  + (size_t)(rowB + srow)*K + sc8*8;
  const unsigned short* gB = Bt + (size_t)(colB + srow)*K + sc8*8;
  const int woff = wave*2048 + lane*8;

  floatx4 acc[4][4];
#pragma unroll
  for (int t=0;t<4;t++)
#pragma unroll
    for (int u=0;u<4;u++) acc[t][u] = (floatx4){0.f,0.f,0.f,0.f};

  // prologue: stage tile 0 into buffer 0
#pragma unroll
  for (int i=0;i<4;i++){
    async16(gA + (size_t)i*8*K, &lA[0][0] + woff + i*512);
    async16(gB + (size_t)i*8*K, &lB[0][0] + woff + i*512);
  }
  __syncthreads();                       // implicit vmcnt(0) before barrier

  int cur = 0;
  for (int kt = 0; kt < K; kt += 64){
    if (kt + 64 < K){                    // issue next tile -> other buffer
      unsigned short* an = (cur ? &lA[0][0] : &lA[1][0]) + woff;
      unsigned short* bn = (cur ? &lB[0][0] : &lB[1][0]) + woff;
#pragma unroll
      for (int i=0;i<4;i++){
        async16(gA + (size_t)i*8*K + kt + 64, an + i*512);
        async16(gB + (size_t)i*8*K + kt + 64, bn + i*512);
      }
    }
    const unsigned short* sA = cur ? &lA[1][0] : &lA[0][0];
    const unsigned short* sB = cur ? &lB[1][0] : &lB[0][0];
#pragma unroll
    for (int ks=0; ks<2; ks++){
      const int cph = ((ks*4 + quad) ^ (l15 & 7)) * 8;
      short8 af[4], bf[4];
#pragma unroll
      for (int t=0;t<4;t++) af[t] = *(const short8*)(sA + (wR + t*16 + l15)*64 + cph);
#pragma unroll
      for (int u=0;u<4;u++) bf[u] = *(const short8*)(sB + (wC + u*16 + l15)*64 + cph);
#pragma unroll
      for (int t=0;t<4;t++)
#pragma unroll
        for (int u=0;u<4;u++)
          acc[t][u] = __builtin_amdgcn_mfma_f32_16x16x32_bf16(af[t], bf[u], acc[t][u], 0, 0, 0);
    }
    if (kt + 64 < K) __syncthreads();    // one barrier/K-step; none after last
    cur ^= 1;
  }
  // epilogue: C/D layout col = lane&15, row = quad*4 + r  [m89/m91 verified]
  if (MODE == 3 && colB >= 2048){
    // V block: transposed f16 store, 4 consecutive tokens per 8B chunk
#pragma unroll
    for (int u=0;u<4;u++){
      int col = colB + wC + u*16 + l15;
      float bval = bias[col];
      int vcol = col - 2048;
      int hh = vcol >> 6, dv = vcol & 63;
#pragma unroll
      for (int t=0;t<4;t++){
        int row0 = rowB + wR + t*16 + quad*4;       // token of acc[t][u][0]
        int bb = row0 >> 11, s = row0 & 2047;
        union { pk2 p[2]; short4v s4; } cv;
        cv.p[0] = __builtin_amdgcn_cvt_pkrtz(acc[t][u][0]+bval, acc[t][u][1]+bval);
        cv.p[1] = __builtin_amdgcn_cvt_pkrtz(acc[t][u][2]+bval, acc[t][u][3]+bval);
        *(short4v*)(Vt + ((size_t)(bb*16+hh)*64 + dv)*2048 + s) = cv.s4;
      }
    }
  } else {
#pragma unroll
    for (int u=0;u<4;u++){
      int col = colB + wC + u*16 + l15;
      float bval = bias[col];
      float scale = (MODE == 3 && col < 1024) ? QSCALE : 1.0f;
#pragma unroll
      for (int t=0;t<4;t++){
        int row0 = rowB + wR + t*16 + quad*4;
#pragma unroll
        for (int r=0;r<4;r++){
          float val = (acc[t][u][r] + bval) * scale;
          if (MODE == 1) ((float*)Cv)[(size_t)(row0 + r)*N + col] = val;
          else ((unsigned short*)Cv)[(size_t)(row0 + r)*N + col] = f2b(val);
        }
      }
    }
  }
}

// ---------------- flash attention forward, S^T formulation -----------------
// R9/R10 (verified): QBLK=256, 8 waves, true double-buffer, 1 barrier/tile,
// sigma-staged K -> in-lane full-rate x32 f16 PV, ones-column MFMA softmax
// denominator, V in per-half [64][64] sub-arrays (zero bank conflicts).
__global__ __launch_bounds__(512) void flash_attn_kernel(
    const unsigned short* __restrict__ qkv,
    const unsigned short* __restrict__ vt,      // f16 bits, [bh*64+dv][token]
    unsigned short* __restrict__ attn_out)      // bf16
{
  __shared__ __align__(16) unsigned short sK [2][128][64];    // bf16 [buf][sigma(kv)][dk]
  __shared__ __align__(16) unsigned short sVt[2][2][64][64];  // f16  [buf][hf][dv][kv64]
  const int bh = blockIdx.x;
  const int b = bh >> 4, h = bh & 15;
  const int qt = blockIdx.y;
  const int tid = threadIdx.x;
  const int wave = tid >> 6;
  const int lane = tid & 63;
  const int quad = lane >> 4, l15 = lane & 15;
  const int tok0 = b*SEQ + qt*256;

  // Q B-fragments straight from global (n = q = l15, k contiguous)
  short8 qf[2][2];
#pragma unroll
  for (int t=0;t<2;t++)
#pragma unroll
    for (int ks=0;ks<2;ks++)
      qf[t][ks] = *(const short8*)(qkv + (size_t)(tok0 + wave*32 + t*16 + l15)*3072
                                   + h*64 + ks*32 + quad*8);

  floatx4 oacc[2][4];
  floatx4 dacc[2];
#pragma unroll
  for (int t=0;t<2;t++){
    dacc[t] = (floatx4){0.f,0.f,0.f,0.f};
#pragma unroll
    for (int v=0;v<4;v++) oacc[t][v] = (floatx4){0.f,0.f,0.f,0.f};
  }
  const _Float16 one_h = (_Float16)1.0f;
  const half8 ones = {one_h,one_h,one_h,one_h,one_h,one_h,one_h,one_h};

  // staging descriptors: 2 K-chunks + 2 V-chunks per thread (512 threads).
  // K: [128 kv][64 dk]; row sigma-permuted (bits 5,6 pass through), chunk
  // XOR-swizzled by physical row &7.
  // V: [hf][64 dv][64 kv]; chunk c3 XOR dv&7 within the hf sub-array.
  const unsigned short* kbase[2]; const unsigned short* vbase[2];
  int KD[2], VD[2];
#pragma unroll
  for (int i=0;i<2;i++){
    int c = tid + i*512;
    int kr = c >> 3, kc = c & 7;
    int sr = (kr & 96) | ((kr & 4) << 2) | ((kr >> 1) & 12) | (kr & 3);
    kbase[i] = qkv + (size_t)(b*SEQ + kr)*3072 + 1024 + h*64 + kc*8;
    KD[i] = sr*64 + ((kc ^ (sr & 7)) * 8);
    int dv = c >> 4, vc = c & 15;
    int hfb = vc >> 3, c3 = vc & 7;
    vbase[i] = vt + (size_t)(bh*64 + dv)*2048 + vc*8;
    VD[i] = hfb*4096 + dv*64 + ((c3 ^ (dv & 7)) * 8);
  }
  short8 rk[2], rv[2];
  // prefetch tile 0
#pragma unroll
  for (int i=0;i<2;i++){
    rk[i] = *(const short8*)(kbase[i]);
    rv[i] = *(const short8*)(vbase[i]);
  }

  for (int it = 0; it < SEQ/128; it++){
    unsigned short* sKb = &sK [it & 1][0][0];
    unsigned short* sVb = &sVt[it & 1][0][0][0];
#pragma unroll
    for (int i=0;i<2;i++){
      *(short8*)(sKb + KD[i]) = rk[i];
      *(short8*)(sVb + VD[i]) = rv[i];
    }
    __syncthreads();
    if (it + 1 < SEQ/128){             // issue next-tile loads (in flight
      int nx = (it + 1) * 128;         //  across the whole compute phase)
#pragma unroll
      for (int i=0;i<2;i++){
        rk[i] = *(const short8*)(kbase[i] + (size_t)nx*3072);
        rv[i] = *(const short8*)(vbase[i] + nx);
      }
    }

#pragma unroll
    for (int hf=0; hf<2; hf++){
      // S^T[srow][q]: A = K (m = sigma(kv)), B = Q (n = q = l15).
      floatx4 sacc[4][2];
#pragma unroll
      for (int u=0;u<4;u++)
#pragma unroll
        for (int t=0;t<2;t++) sacc[u][t] = (floatx4){0.f,0.f,0.f,0.f};
#pragma unroll
      for (int ks=0;ks<2;ks++){
        short8 kf[4];
#pragma unroll
        for (int u=0;u<4;u++)
          kf[u] = *(const short8*)(sKb + (hf*64 + u*16 + l15)*64
                                   + ((ks*4 + quad) ^ (l15 & 7)) * 8);
#pragma unroll
        for (int u=0;u<4;u++)
#pragma unroll
          for (int t=0;t<2;t++)
            sacc[u][t] = __builtin_amdgcn_mfma_f32_16x16x32_bf16(kf[u], qf[t][ks], sacc[u][t], 0,0,0);
      }

      // p = 2^s; sacc[u][t] reg r holds kv = 32*(u>>1) + 8*quad + 4*(u&1) + r
      unsigned pw[4][2][2];
#pragma unroll
      for (int t=0;t<2;t++){
#pragma unroll
        for (int u=0;u<4;u++){
          float p0 = __builtin_amdgcn_exp2f(sacc[u][t][0]);
          float p1 = __builtin_amdgcn_exp2f(sacc[u][t][1]);
          float p2 = __builtin_amdgcn_exp2f(sacc[u][t][2]);
          float p3 = __builtin_amdgcn_exp2f(sacc[u][t][3]);
          union { pk2 p; unsigned u32; } c0, c1;
          c0.p = __builtin_amdgcn_cvt_pkrtz(p0,p1);
          c1.p = __builtin_amdgcn_cvt_pkrtz(p2,p3);
          pw[u][t][0] = c0.u32; pw[u][t][1] = c1.u32;
        }
      }
      // x32 f16 A-frags: pf[t][B] elem j = P[q][kv=32B+8quad+j], in-lane
      half8 pf[2][2];
#pragma unroll
      for (int t=0;t<2;t++)
#pragma unroll
        for (int B=0;B<2;B++){
          union { unsigned u32[4]; half8 h; } a;
          a.u32[0] = pw[2*B  ][t][0]; a.u32[1] = pw[2*B  ][t][1];
          a.u32[2] = pw[2*B+1][t][0]; a.u32[3] = pw[2*B+1][t][1];
          pf[t][B] = a.h;
        }

      // softmax denominator via ones-column MFMA: dacc rows q-aligned w/ oacc
#pragma unroll
      for (int t=0;t<2;t++)
#pragma unroll
        for (int B=0;B<2;B++)
          dacc[t] = __builtin_amdgcn_mfma_f32_16x16x32_f16(pf[t][B], ones, dacc[t], 0,0,0);

      // O[q][dv] += P V : B-frag = V[kv=32B+8quad+j][dv=v*16+l15], one b128
      // from the hf sub-array (128B rows — zero-conflict verified geometry)
#pragma unroll
      for (int v=0;v<4;v++){
#pragma unroll
        for (int B=0;B<2;B++){
          union { short8 s; half8 h; } vb;
          vb.s = *(const short8*)(sVb + hf*4096 + (v*16 + l15)*64
                                  + ((B*4 + quad) ^ (l15 & 7)) * 8);
#pragma unroll
          for (int t=0;t<2;t++)
            oacc[t][v] = __builtin_amdgcn_mfma_f32_16x16x32_f16(pf[t][B], vb.h, oacc[t][v], 0,0,0);
        }
      }
    }
  }

  // epilogue: O rows are q local = quad*4+r; dacc[t][r] holds that row's sum
#pragma unroll
  for (int t=0;t<2;t++){
#pragma unroll
    for (int r=0;r<4;r++){
      float inv = 1.0f / dacc[t][r];
      int tok = tok0 + wave*32 + t*16 + quad*4 + r;
#pragma unroll
      for (int v=0;v<4;v++)
        attn_out[(size_t)tok*1024 + h*64 + v*16 + l15] = f2b(oacc[t][v][r] * inv);
    }
  }
}

extern "C" void kernel_launch(void* const* d_in, const int* in_sizes, int n_in,
                              void* d_out, int out_size, void* d_ws, size_t ws_size,
                              hipStream_t stream)
{
  const float* x  = (const float*)d_in[0];
  const float* wq = (const float*)d_in[1];
  const float* bq = (const float*)d_in[2];
  const float* wk = (const float*)d_in[3];
  const float* bk = (const float*)d_in[4];
  const float* wv = (const float*)d_in[5];
  const float* bv = (const float*)d_in[6];
  const float* wo = (const float*)d_in[7];
  const float* bo = (const float*)d_in[8];
  float* out = (float*)d_out;

  char* ws = (char*)d_ws;
  unsigned short* wqkvT  = (unsigned short*)(ws);               // 3072x1024 bf16
  unsigned short* woT    = (unsigned short*)(ws + 6291456);     // 1024x1024 bf16
  float*          bqkv   = (float*)(ws + 8388608);              // 3072 f32
  unsigned short* xb     = (unsigned short*)(ws + 8400896);     // 8192x1024 bf16
  unsigned short* qkvbuf = (unsigned short*)(ws + 25178112);    // 8192x3072 bf16 (V region unused)
  unsigned short* vtbuf  = (unsigned short*)(ws + 75509760);    // 4096x2048 f16
  unsigned short* aobuf  = (unsigned short*)(ws + 92286976);    // 8192x1024 bf16

  prep_kernel<<<dim3(9228), 256, 0, stream>>>(x, wq, wk, wv, wo, bq, bk, bv,
                                              xb, wqkvT, woT, bqkv);
  gemm_bt_kernel<3><<<dim3(24, 64), 256, 0, stream>>>(xb, wqkvT, bqkv, qkvbuf, vtbuf,
                                                      8192, 3072, 1024);
  flash_attn_kernel<<<dim3(64, 8), 512, 0, stream>>>(qkvbuf, vtbuf, aobuf);
  gemm_bt_kernel<1><<<dim3(8, 64), 256, 0, stream>>>(aobuf, woT, bo, out, nullptr,
                                                     8192, 1024, 1024);
}

// Round 13
// 255.757 us; speedup vs baseline: 1.2710x; 1.0819x over previous
//
#include <hip/hip_runtime.h>
#include <stdint.h>

typedef __attribute__((ext_vector_type(8))) short short8;
typedef __attribute__((ext_vector_type(4))) short short4v;
typedef __attribute__((ext_vector_type(4))) float floatx4;
typedef __attribute__((ext_vector_type(8))) _Float16 half8;
typedef __attribute__((ext_vector_type(2))) __fp16 pk2;

#define SEQ 2048
#define NTOK 8192
// 0.25 * log2(e): folds the 1/sqrt(H) quirk-scale and exp->exp2 into Q proj.
#define QSCALE 0.360673760222241f

__device__ __forceinline__ float b2f(unsigned short u){
  union { unsigned int i; float f; } v; v.i = ((unsigned int)u) << 16; return v.f;
}
__device__ __forceinline__ unsigned short f2b(float f){
  union { float f; unsigned int i; } v; v.f = f;
  unsigned int r = v.i + 0x7fffu + ((v.i >> 16) & 1u);
  return (unsigned short)(r >> 16);
}
// async global->LDS, 16B per lane. Dest = wave-uniform base + lane*16.
__device__ __forceinline__ void async16(const unsigned short* g, unsigned short* l){
  __builtin_amdgcn_global_load_lds(
      (const __attribute__((address_space(1))) unsigned int*)g,
      (__attribute__((address_space(3))) unsigned int*)l, 16, 0, 0);
}

// ---------- fused prep: convert_x | transpose_w | bias_concat --------------
__global__ __launch_bounds__(256) void prep_kernel(
    const float* __restrict__ x,
    const float* __restrict__ wq, const float* __restrict__ wk,
    const float* __restrict__ wv, const float* __restrict__ wo,
    const float* __restrict__ bq, const float* __restrict__ bk,
    const float* __restrict__ bv,
    unsigned short* __restrict__ xb,
    unsigned short* __restrict__ wqkvT, unsigned short* __restrict__ woT,
    float* __restrict__ bqkv)
{
  __shared__ unsigned short lT[64][72];
  const int bid = blockIdx.x;
  const int tid = threadIdx.x;
  if (bid < 8192){
    int i = (bid*256 + tid)*4;
    float4 v = *(const float4*)(x + i);
    short4v o;
    o[0] = (short)f2b(v.x); o[1] = (short)f2b(v.y);
    o[2] = (short)f2b(v.z); o[3] = (short)f2b(v.w);
    *(short4v*)(xb + i) = o;
  } else if (bid < 9216){
    int idx = bid - 8192;
    int sel = idx >> 8, rest = idx & 255;
    const float* src = (sel==0)?wq:(sel==1)?wk:(sel==2)?wv:wo;
    unsigned short* dst = (sel<3) ? (wqkvT + (size_t)sel*1024*1024) : woT;
    int n0 = (rest & 15) * 64, k0 = (rest >> 4) * 64;
#pragma unroll
    for (int i=0;i<4;i++){
      int ch = tid + i*256;
      int r = ch>>4, c = (ch&15)*4;
      float4 v = *(const float4*)(src + (size_t)(k0+r)*1024 + n0 + c);
      lT[r][c+0] = f2b(v.x); lT[r][c+1] = f2b(v.y);
      lT[r][c+2] = f2b(v.z); lT[r][c+3] = f2b(v.w);
    }
    __syncthreads();
#pragma unroll
    for (int i=0;i<2;i++){
      int ch = tid + i*256;
      int rn = ch>>3, c = (ch&7)*8;
      short8 v;
#pragma unroll
      for (int j=0;j<8;j++) v[j] = (short)lT[c+j][rn];
      *(short8*)(dst + (size_t)(n0+rn)*1024 + k0 + c) = v;
    }
  } else {
    int i = (bid - 9216)*256 + tid;
    if (i < 3072){
      int sel = i >> 10, j = i & 1023;
      bqkv[i] = (sel==0)?bq[j]:(sel==1)?bk[j]:bv[j];
    }
  }
}

// ---------------- GEMM: C(MxN) = A(MxK) @ Bt(NxK)^T + bias ----------------
// MODE 1: f32 store. MODE 3: QKV fused — cols<1024 bf16*QSCALE, 1024..2047
// bf16, >=2048 (V) written f16 TRANSPOSED into Vt[(b*16+h)*64+dv][s].
// R13: EXACT R10 schedule (best measured, total 266.5us). 2 LDS buffers;
// issue next tile -> buf[cur^1] at top of compute; ONE UNCONDITIONAL
// __syncthreads() per K-step. R12's conditional last-iter barrier skip
// regressed ~17us (compiler restructures the loop when the barrier is
// control-dependent — do NOT make it conditional). R11's 3-buffer depth-2
// dropped occupancy to 1 wave/SIMD and regressed 66->119us.
template<int MODE>
__global__ __launch_bounds__(256) void gemm_bt_kernel(
    const unsigned short* __restrict__ A,
    const unsigned short* __restrict__ Bt,
    const float* __restrict__ bias,
    void* __restrict__ Cv,
    unsigned short* __restrict__ Vt,
    int M, int N, int K)
{
  __shared__ unsigned short lA[2][128*64];
  __shared__ unsigned short lB[2][128*64];
  const int tid  = threadIdx.x;
  const int lane = tid & 63;
  const int wave = tid >> 6;
  const int quad = lane >> 4;
  const int l15  = lane & 15;
  const int wR = (wave >> 1) * 64;
  const int wC = (wave & 1) * 64;
  const int rowB = blockIdx.y * 128;
  const int colB = blockIdx.x * 128;

  const int srow = wave*32 + (lane>>3);
  const int sc8  = (lane&7) ^ (lane>>3);
  const unsigned short* gA = A  + (size_t)(rowB + srow)*K + sc8*8;
  const unsigned short* gB = Bt + (size_t)(colB + srow)*K + sc8*8;
  const int woff = wave*2048 + lane*8;

  floatx4 acc[4][4];
#pragma unroll
  for (int t=0;t<4;t++)
#pragma unroll
    for (int u=0;u<4;u++) acc[t][u] = (floatx4){0.f,0.f,0.f,0.f};

  // prologue: stage tile 0 into buffer 0
#pragma unroll
  for (int i=0;i<4;i++){
    async16(gA + (size_t)i*8*K, &lA[0][0] + woff + i*512);
    async16(gB + (size_t)i*8*K, &lB[0][0] + woff + i*512);
  }
  __syncthreads();                       // implicit vmcnt(0) before barrier

  int cur = 0;
  for (int kt = 0; kt < K; kt += 64){
    if (kt + 64 < K){                    // issue next tile -> other buffer
      unsigned short* an = (cur ? &lA[0][0] : &lA[1][0]) + woff;
      unsigned short* bn = (cur ? &lB[0][0] : &lB[1][0]) + woff;
#pragma unroll
      for (int i=0;i<4;i++){
        async16(gA + (size_t)i*8*K + kt + 64, an + i*512);
        async16(gB + (size_t)i*8*K + kt + 64, bn + i*512);
      }
    }
    const unsigned short* sA = cur ? &lA[1][0] : &lA[0][0];
    const unsigned short* sB = cur ? &lB[1][0] : &lB[0][0];
#pragma unroll
    for (int ks=0; ks<2; ks++){
      const int cph = ((ks*4 + quad) ^ (l15 & 7)) * 8;
      short8 af[4], bf[4];
#pragma unroll
      for (int t=0;t<4;t++) af[t] = *(const short8*)(sA + (wR + t*16 + l15)*64 + cph);
#pragma unroll
      for (int u=0;u<4;u++) bf[u] = *(const short8*)(sB + (wC + u*16 + l15)*64 + cph);
#pragma unroll
      for (int t=0;t<4;t++)
#pragma unroll
        for (int u=0;u<4;u++)
          acc[t][u] = __builtin_amdgcn_mfma_f32_16x16x32_bf16(af[t], bf[u], acc[t][u], 0, 0, 0);
    }
    __syncthreads();                     // one barrier/K-step; drain after compute
    cur ^= 1;
  }
  // epilogue: C/D layout col = lane&15, row = quad*4 + r  [m89/m91 verified]
  if (MODE == 3 && colB >= 2048){
    // V block: transposed f16 store, 4 consecutive tokens per 8B chunk
#pragma unroll
    for (int u=0;u<4;u++){
      int col = colB + wC + u*16 + l15;
      float bval = bias[col];
      int vcol = col - 2048;
      int hh = vcol >> 6, dv = vcol & 63;
#pragma unroll
      for (int t=0;t<4;t++){
        int row0 = rowB + wR + t*16 + quad*4;       // token of acc[t][u][0]
        int bb = row0 >> 11, s = row0 & 2047;
        union { pk2 p[2]; short4v s4; } cv;
        cv.p[0] = __builtin_amdgcn_cvt_pkrtz(acc[t][u][0]+bval, acc[t][u][1]+bval);
        cv.p[1] = __builtin_amdgcn_cvt_pkrtz(acc[t][u][2]+bval, acc[t][u][3]+bval);
        *(short4v*)(Vt + ((size_t)(bb*16+hh)*64 + dv)*2048 + s) = cv.s4;
      }
    }
  } else {
#pragma unroll
    for (int u=0;u<4;u++){
      int col = colB + wC + u*16 + l15;
      float bval = bias[col];
      float scale = (MODE == 3 && col < 1024) ? QSCALE : 1.0f;
#pragma unroll
      for (int t=0;t<4;t++){
        int row0 = rowB + wR + t*16 + quad*4;
#pragma unroll
        for (int r=0;r<4;r++){
          float val = (acc[t][u][r] + bval) * scale;
          if (MODE == 1) ((float*)Cv)[(size_t)(row0 + r)*N + col] = val;
          else ((unsigned short*)Cv)[(size_t)(row0 + r)*N + col] = f2b(val);
        }
      }
    }
  }
}

// ---------------- flash attention forward, S^T formulation -----------------
// R9/R10 (verified): QBLK=256, 8 waves, true double-buffer, 1 barrier/tile,
// sigma-staged K -> in-lane full-rate x32 f16 PV, ones-column MFMA softmax
// denominator, V in per-half [64][64] sub-arrays (zero bank conflicts).
__global__ __launch_bounds__(512) void flash_attn_kernel(
    const unsigned short* __restrict__ qkv,
    const unsigned short* __restrict__ vt,      // f16 bits, [bh*64+dv][token]
    unsigned short* __restrict__ attn_out)      // bf16
{
  __shared__ __align__(16) unsigned short sK [2][128][64];    // bf16 [buf][sigma(kv)][dk]
  __shared__ __align__(16) unsigned short sVt[2][2][64][64];  // f16  [buf][hf][dv][kv64]
  const int bh = blockIdx.x;
  const int b = bh >> 4, h = bh & 15;
  const int qt = blockIdx.y;
  const int tid = threadIdx.x;
  const int wave = tid >> 6;
  const int lane = tid & 63;
  const int quad = lane >> 4, l15 = lane & 15;
  const int tok0 = b*SEQ + qt*256;

  // Q B-fragments straight from global (n = q = l15, k contiguous)
  short8 qf[2][2];
#pragma unroll
  for (int t=0;t<2;t++)
#pragma unroll
    for (int ks=0;ks<2;ks++)
      qf[t][ks] = *(const short8*)(qkv + (size_t)(tok0 + wave*32 + t*16 + l15)*3072
                                   + h*64 + ks*32 + quad*8);

  floatx4 oacc[2][4];
  floatx4 dacc[2];
#pragma unroll
  for (int t=0;t<2;t++){
    dacc[t] = (floatx4){0.f,0.f,0.f,0.f};
#pragma unroll
    for (int v=0;v<4;v++) oacc[t][v] = (floatx4){0.f,0.f,0.f,0.f};
  }
  const _Float16 one_h = (_Float16)1.0f;
  const half8 ones = {one_h,one_h,one_h,one_h,one_h,one_h,one_h,one_h};

  // staging descriptors: 2 K-chunks + 2 V-chunks per thread (512 threads).
  // K: [128 kv][64 dk]; row sigma-permuted (bits 5,6 pass through), chunk
  // XOR-swizzled by physical row &7.
  // V: [hf][64 dv][64 kv]; chunk c3 XOR dv&7 within the hf sub-array.
  const unsigned short* kbase[2]; const unsigned short* vbase[2];
  int KD[2], VD[2];
#pragma unroll
  for (int i=0;i<2;i++){
    int c = tid + i*512;
    int kr = c >> 3, kc = c & 7;
    int sr = (kr & 96) | ((kr & 4) << 2) | ((kr >> 1) & 12) | (kr & 3);
    kbase[i] = qkv + (size_t)(b*SEQ + kr)*3072 + 1024 + h*64 + kc*8;
    KD[i] = sr*64 + ((kc ^ (sr & 7)) * 8);
    int dv = c >> 4, vc = c & 15;
    int hfb = vc >> 3, c3 = vc & 7;
    vbase[i] = vt + (size_t)(bh*64 + dv)*2048 + vc*8;
    VD[i] = hfb*4096 + dv*64 + ((c3 ^ (dv & 7)) * 8);
  }
  short8 rk[2], rv[2];
  // prefetch tile 0
#pragma unroll
  for (int i=0;i<2;i++){
    rk[i] = *(const short8*)(kbase[i]);
    rv[i] = *(const short8*)(vbase[i]);
  }

  for (int it = 0; it < SEQ/128; it++){
    unsigned short* sKb = &sK [it & 1][0][0];
    unsigned short* sVb = &sVt[it & 1][0][0][0];
#pragma unroll
    for (int i=0;i<2;i++){
      *(short8*)(sKb + KD[i]) = rk[i];
      *(short8*)(sVb + VD[i]) = rv[i];
    }
    __syncthreads();
    if (it + 1 < SEQ/128){             // issue next-tile loads (in flight
      int nx = (it + 1) * 128;         //  across the whole compute phase)
#pragma unroll
      for (int i=0;i<2;i++){
        rk[i] = *(const short8*)(kbase[i] + (size_t)nx*3072);
        rv[i] = *(const short8*)(vbase[i] + nx);
      }
    }

#pragma unroll
    for (int hf=0; hf<2; hf++){
      // S^T[srow][q]: A = K (m = sigma(kv)), B = Q (n = q = l15).
      floatx4 sacc[4][2];
#pragma unroll
      for (int u=0;u<4;u++)
#pragma unroll
        for (int t=0;t<2;t++) sacc[u][t] = (floatx4){0.f,0.f,0.f,0.f};
#pragma unroll
      for (int ks=0;ks<2;ks++){
        short8 kf[4];
#pragma unroll
        for (int u=0;u<4;u++)
          kf[u] = *(const short8*)(sKb + (hf*64 + u*16 + l15)*64
                                   + ((ks*4 + quad) ^ (l15 & 7)) * 8);
#pragma unroll
        for (int u=0;u<4;u++)
#pragma unroll
          for (int t=0;t<2;t++)
            sacc[u][t] = __builtin_amdgcn_mfma_f32_16x16x32_bf16(kf[u], qf[t][ks], sacc[u][t], 0,0,0);
      }

      // p = 2^s; sacc[u][t] reg r holds kv = 32*(u>>1) + 8*quad + 4*(u&1) + r
      unsigned pw[4][2][2];
#pragma unroll
      for (int t=0;t<2;t++){
#pragma unroll
        for (int u=0;u<4;u++){
          float p0 = __builtin_amdgcn_exp2f(sacc[u][t][0]);
          float p1 = __builtin_amdgcn_exp2f(sacc[u][t][1]);
          float p2 = __builtin_amdgcn_exp2f(sacc[u][t][2]);
          float p3 = __builtin_amdgcn_exp2f(sacc[u][t][3]);
          union { pk2 p; unsigned u32; } c0, c1;
          c0.p = __builtin_amdgcn_cvt_pkrtz(p0,p1);
          c1.p = __builtin_amdgcn_cvt_pkrtz(p2,p3);
          pw[u][t][0] = c0.u32; pw[u][t][1] = c1.u32;
        }
      }
      // x32 f16 A-frags: pf[t][B] elem j = P[q][kv=32B+8quad+j], in-lane
      half8 pf[2][2];
#pragma unroll
      for (int t=0;t<2;t++)
#pragma unroll
        for (int B=0;B<2;B++){
          union { unsigned u32[4]; half8 h; } a;
          a.u32[0] = pw[2*B  ][t][0]; a.u32[1] = pw[2*B  ][t][1];
          a.u32[2] = pw[2*B+1][t][0]; a.u32[3] = pw[2*B+1][t][1];
          pf[t][B] = a.h;
        }

      // softmax denominator via ones-column MFMA: dacc rows q-aligned w/ oacc
#pragma unroll
      for (int t=0;t<2;t++)
#pragma unroll
        for (int B=0;B<2;B++)
          dacc[t] = __builtin_amdgcn_mfma_f32_16x16x32_f16(pf[t][B], ones, dacc[t], 0,0,0);

      // O[q][dv] += P V : B-frag = V[kv=32B+8quad+j][dv=v*16+l15], one b128
      // from the hf sub-array (128B rows — zero-conflict verified geometry)
#pragma unroll
      for (int v=0;v<4;v++){
#pragma unroll
        for (int B=0;B<2;B++){
          union { short8 s; half8 h; } vb;
          vb.s = *(const short8*)(sVb + hf*4096 + (v*16 + l15)*64
                                  + ((B*4 + quad) ^ (l15 & 7)) * 8);
#pragma unroll
          for (int t=0;t<2;t++)
            oacc[t][v] = __builtin_amdgcn_mfma_f32_16x16x32_f16(pf[t][B], vb.h, oacc[t][v], 0,0,0);
        }
      }
    }
  }

  // epilogue: O rows are q local = quad*4+r; dacc[t][r] holds that row's sum
#pragma unroll
  for (int t=0;t<2;t++){
#pragma unroll
    for (int r=0;r<4;r++){
      float inv = 1.0f / dacc[t][r];
      int tok = tok0 + wave*32 + t*16 + quad*4 + r;
#pragma unroll
      for (int v=0;v<4;v++)
        attn_out[(size_t)tok*1024 + h*64 + v*16 + l15] = f2b(oacc[t][v][r] * inv);
    }
  }
}

extern "C" void kernel_launch(void* const* d_in, const int* in_sizes, int n_in,
                              void* d_out, int out_size, void* d_ws, size_t ws_size,
                              hipStream_t stream)
{
  const float* x  = (const float*)d_in[0];
  const float* wq = (const float*)d_in[1];
  const float* bq = (const float*)d_in[2];
  const float* wk = (const float*)d_in[3];
  const float* bk = (const float*)d_in[4];
  const float* wv = (const float*)d_in[5];
  const float* bv = (const float*)d_in[6];
  const float* wo = (const float*)d_in[7];
  const float* bo = (const float*)d_in[8];
  float* out = (float*)d_out;

  char* ws = (char*)d_ws;
  unsigned short* wqkvT  = (unsigned short*)(ws);               // 3072x1024 bf16
  unsigned short* woT    = (unsigned short*)(ws + 6291456);     // 1024x1024 bf16
  float*          bqkv   = (float*)(ws + 8388608);              // 3072 f32
  unsigned short* xb     = (unsigned short*)(ws + 8400896);     // 8192x1024 bf16
  unsigned short* qkvbuf = (unsigned short*)(ws + 25178112);    // 8192x3072 bf16 (V region unused)
  unsigned short* vtbuf  = (unsigned short*)(ws + 75509760);    // 4096x2048 f16
  unsigned short* aobuf  = (unsigned short*)(ws + 92286976);    // 8192x1024 bf16

  prep_kernel<<<dim3(9228), 256, 0, stream>>>(x, wq, wk, wv, wo, bq, bk, bv,
                                              xb, wqkvT, woT, bqkv);
  gemm_bt_kernel<3><<<dim3(24, 64), 256, 0, stream>>>(xb, wqkvT, bqkv, qkvbuf, vtbuf,
                                                      8192, 3072, 1024);
  flash_attn_kernel<<<dim3(64, 8), 512, 0, stream>>>(qkvbuf, vtbuf, aobuf);
  gemm_bt_kernel<1><<<dim3(8, 64), 256, 0, stream>>>(aobuf, woT, bo, out, nullptr,
                                                     8192, 1024, 1024);
}